// Round 13
// baseline (239.679 us; speedup 1.0000x reference)
//
#include <hip/hip_runtime.h>
#include <hip/hip_bf16.h>

// Problem constants
#define B 64
#define D 1024
#define H 1024
#define C 32           // chunks along D
#define L (D / C)      // chunk length = 32
#define BG 4           // batch rows per main block
#define NBG (B / BG)   // 16 batch groups
#define HQ 4           // h-quarters
#define HP (H / HQ)    // 256 h per block = 1 h per thread

// DPP quad-perm cross-lane (VALU-speed, no LDS)
__device__ __forceinline__ float dpp_xor1(float v) {
    int i = __builtin_bit_cast(int, v);
    i = __builtin_amdgcn_mov_dpp(i, 0xB1, 0xF, 0xF, true);  // quad_perm [1,0,3,2]
    return __builtin_bit_cast(float, i);
}
__device__ __forceinline__ float dpp_xor2(float v) {
    int i = __builtin_bit_cast(int, v);
    i = __builtin_amdgcn_mov_dpp(i, 0x4E, 0xF, 0xF, true);  // quad_perm [2,3,0,1]
    return __builtin_bit_cast(float, i);
}

// round-to-nearest-even f32 -> bf16 bits (low 16)
__device__ __forceinline__ unsigned bf16r(float f) {
    unsigned u = __builtin_bit_cast(unsigned, f);
    return (u + 0x7FFFu + ((u >> 16) & 1u)) >> 16;
}

// ---------------------------------------------------------------------------
// Kernel 0: pack PK[d][h] = bf16(h_W[d,h])<<16 | bf16(in_W[h,d])
// ---------------------------------------------------------------------------
__global__ void k_pack(const float* __restrict__ in_W,
                       const float* __restrict__ h_W,
                       unsigned* __restrict__ PK) {
    __shared__ float tile[32][33];
    int bx = blockIdx.x * 32;  // d-range
    int by = blockIdx.y * 32;  // h-range
    int tx = threadIdx.x;      // 0..31
    int ty = threadIdx.y;      // 0..7
    #pragma unroll
    for (int r = 0; r < 32; r += 8)
        tile[ty + r][tx] = in_W[(size_t)(by + ty + r) * D + (bx + tx)];
    __syncthreads();
    #pragma unroll
    for (int r = 0; r < 32; r += 8) {
        int d = bx + ty + r;
        int h = by + tx;
        float hw = h_W[(size_t)d * H + h];       // coalesced in tx
        float iw = tile[tx][ty + r];             // in_W[h][d]
        PK[(size_t)d * H + h] = (bf16r(hw) << 16) | bf16r(iw);
    }
}

// ---------------------------------------------------------------------------
// Kernel 1: direct exclusive per-chunk prefix (replaces chunk_sums + scan).
// block = (b, hq): 256 blocks, 256 threads; thread owns one h.
// P[b][c][h] = in_b[h] + sum_{d < c*L} x[b,d] * in_W[h,d]
// PK loads coalesced across threads; x row staged in LDS; serial FMA chain.
// Also zeroes the main kernel's combine counters (block 0).
// ---------------------------------------------------------------------------
__global__ void __launch_bounds__(256)
k_prefix(const float* __restrict__ x,
         const unsigned* __restrict__ PK,
         const float* __restrict__ in_b,
         float* __restrict__ P,
         int* __restrict__ cnt) {
    int blk = blockIdx.x;
    int b  = blk >> 2;         // 0..63
    int hq = blk & 3;          // 0..3
    int tid = threadIdx.x;
    int h  = hq * HP + tid;

    if (blk == 0) { cnt[tid] = 0; cnt[tid + 256] = 0; }   // 512 counters

    __shared__ float xs[D];
    {
        const float4* xrow = reinterpret_cast<const float4*>(&x[(size_t)b * D]);
        float4 v = xrow[tid];
        reinterpret_cast<float4*>(xs)[tid] = v;
    }
    __syncthreads();

    float run = in_b[h];
    #pragma unroll 1
    for (int c = 0; c < C; ++c) {
        P[((size_t)b * C + c) * H + h] = run;
        #pragma unroll
        for (int j = 0; j < L; ++j) {
            int d = c * L + j;
            unsigned pk = PK[(size_t)d * H + h];
            float w = __builtin_bit_cast(float, pk << 16);   // in_W[h,d]
            run = fmaf(xs[d], w, run);
        }
    }
}

// ---------------------------------------------------------------------------
// Kernel 2: main NADE chain + fused combine (last-block pattern).
// block = (bg, c, hq); thread owns one h; 4 batch rows per thread; one packed
// weight load per iteration; barrier-free inner loop (quad-DPP reduce +
// keeper-lane stash, predicated FMA recurrence). Writes Q[hq][b][d]; the
// last-arriving of the 4 hq blocks per (bg,c) combines + sigmoid -> out.
// ---------------------------------------------------------------------------
__global__ void __launch_bounds__(256)
k_nade_main(const float* __restrict__ x,
            const unsigned* __restrict__ PK,
            const float* __restrict__ P,   // prefixes incl. in_b [B,C,H]
            const float* __restrict__ h_b,
            float* __restrict__ Q,         // [HQ][B][D] partial dots
            int* __restrict__ cnt,         // [NBG*C] combine counters
            float* __restrict__ out) {
    int blk = blockIdx.x;
    int bg  = blk >> 7;
    int chq = blk & 127;
    int c   = chq >> 2;
    int hq  = chq & 3;
    int b0  = bg * BG;
    int tid = threadIdx.x;
    int h   = hq * HP + tid;
    int lane = tid & 63;
    int wv = tid >> 6;
    int ph = lane & 3;

    __shared__ float4 xs4[L];
    __shared__ float red[4][BG][L];
    __shared__ int lastFlag;
    if (tid < L) {
        int i = c * L + tid;
        xs4[tid] = make_float4(x[(size_t)b0 * D + i],
                               x[(size_t)(b0 + 1) * D + i],
                               x[(size_t)(b0 + 2) * D + i],
                               x[(size_t)(b0 + 3) * D + i]);
    }

    float a0 = P[((size_t)b0 * C + c) * H + h];
    float a1 = P[((size_t)(b0 + 1) * C + c) * H + h];
    float a2 = P[((size_t)(b0 + 2) * C + c) * H + h];
    float a3 = P[((size_t)(b0 + 3) * C + c) * H + h];

    __syncthreads();

    bool k0 = (ph == 0), k1 = (ph == 1), k2 = (ph == 2), k3 = (ph == 3);

    float pr0[8], pr1[8], pr2[8], pr3[8];
    #pragma unroll
    for (int s = 0; s < 8; ++s) { pr0[s] = 0.f; pr1[s] = 0.f; pr2[s] = 0.f; pr3[s] = 0.f; }

    #pragma unroll
    for (int il = 0; il < L; ++il) {
        int i = c * L + il;
        unsigned pk = PK[(size_t)i * H + h];
        float w  = __builtin_bit_cast(float, pk & 0xFFFF0000u);  // h_W[i,h]
        float wt = __builtin_bit_cast(float, pk << 16);          // in_W[h,i]
        float4 xf = xs4[il];
        int s = il >> 2;
        bool keep = (il & 3) == 0 ? k0 : ((il & 3) == 1 ? k1 : ((il & 3) == 2 ? k2 : k3));

        float p0 = fmaxf(a0, 0.f) * w;
        float t0 = p0 + dpp_xor1(p0); t0 = t0 + dpp_xor2(t0);
        pr0[s] = keep ? t0 : pr0[s];
        a0 = fmaf(xf.x, wt, a0);

        float p1 = fmaxf(a1, 0.f) * w;
        float t1 = p1 + dpp_xor1(p1); t1 = t1 + dpp_xor2(t1);
        pr1[s] = keep ? t1 : pr1[s];
        a1 = fmaf(xf.y, wt, a1);

        float p2 = fmaxf(a2, 0.f) * w;
        float t2 = p2 + dpp_xor1(p2); t2 = t2 + dpp_xor2(t2);
        pr2[s] = keep ? t2 : pr2[s];
        a2 = fmaf(xf.z, wt, a2);

        float p3 = fmaxf(a3, 0.f) * w;
        float t3 = p3 + dpp_xor1(p3); t3 = t3 + dpp_xor2(t3);
        pr3[s] = keep ? t3 : pr3[s];
        a3 = fmaf(xf.w, wt, a3);
    }

    // cross-quad reduce within the wave (sum over 16 quads = 64 h)
    #pragma unroll
    for (int s = 0; s < 8; ++s) {
        float v;
        v = pr0[s];
        v += __shfl_xor(v, 4, 64); v += __shfl_xor(v, 8, 64);
        v += __shfl_xor(v, 16, 64); v += __shfl_xor(v, 32, 64);
        pr0[s] = v;
        v = pr1[s];
        v += __shfl_xor(v, 4, 64); v += __shfl_xor(v, 8, 64);
        v += __shfl_xor(v, 16, 64); v += __shfl_xor(v, 32, 64);
        pr1[s] = v;
        v = pr2[s];
        v += __shfl_xor(v, 4, 64); v += __shfl_xor(v, 8, 64);
        v += __shfl_xor(v, 16, 64); v += __shfl_xor(v, 32, 64);
        pr2[s] = v;
        v = pr3[s];
        v += __shfl_xor(v, 4, 64); v += __shfl_xor(v, 8, 64);
        v += __shfl_xor(v, 16, 64); v += __shfl_xor(v, 32, 64);
        pr3[s] = v;
    }

    if (lane < 4) {
        #pragma unroll
        for (int s = 0; s < 8; ++s) {
            red[wv][0][s * 4 + lane] = pr0[s];
            red[wv][1][s * 4 + lane] = pr1[s];
            red[wv][2][s * 4 + lane] = pr2[s];
            red[wv][3][s * 4 + lane] = pr3[s];
        }
    }
    __syncthreads();

    if (tid < BG * L) {
        int b = tid >> 5;
        int il = tid & 31;
        float t = red[0][b][il] + red[1][b][il] + red[2][b][il] + red[3][b][il];
        Q[((size_t)hq * B + (b0 + b)) * D + c * L + il] = t;
    }

    // ---- fused combine: last of the 4 hq blocks per (bg,c) finishes out ----
    __threadfence();
    __syncthreads();
    if (tid == 0) {
        int old = atomicAdd(&cnt[bg * C + c], 1);
        lastFlag = (old == 3);
    }
    __syncthreads();
    if (lastFlag) {
        __threadfence();   // acquire: see other blocks' Q stores
        if (tid < BG * L) {
            int b = tid >> 5;
            int il = tid & 31;
            int d = c * L + il;
            size_t bb = (size_t)(b0 + b);
            float t = Q[((size_t)0 * B + bb) * D + d]
                    + Q[((size_t)1 * B + bb) * D + d]
                    + Q[((size_t)2 * B + bb) * D + d]
                    + Q[((size_t)3 * B + bb) * D + d]
                    + h_b[d];
            out[bb * D + d] = 1.0f / (1.0f + expf(-t));
        }
    }
}

// ---------------------------------------------------------------------------
extern "C" void kernel_launch(void* const* d_in, const int* in_sizes, int n_in,
                              void* d_out, int out_size, void* d_ws, size_t ws_size,
                              hipStream_t stream) {
    const float* x    = (const float*)d_in[0];  // [B, D]
    const float* in_W = (const float*)d_in[1];  // [H, D]
    const float* in_b = (const float*)d_in[2];  // [H]
    const float* h_W  = (const float*)d_in[3];  // [D, H]
    const float* h_b  = (const float*)d_in[4];  // [D]
    float* out = (float*)d_out;                 // [B, D]

    unsigned* PK = (unsigned*)d_ws;             // [D, H] packed   4 MB
    float* P  = (float*)(PK + (size_t)D * H);   // [B, C, H]       8 MB
    float* Q  = P + (size_t)B * C * H;          // [HQ, B, D]      1 MB
    int*   cnt = (int*)(Q + (size_t)HQ * B * D); // [512]          2 KB

    // 0: pack weights (bf16 pair per dword; includes in_W transpose)
    dim3 tb(32, 8);
    dim3 tg(D / 32, H / 32);
    k_pack<<<tg, tb, 0, stream>>>(in_W, h_W, PK);

    // 1: direct exclusive prefix (replaces chunk_sums + scan); zeroes cnt
    k_prefix<<<B * HQ, 256, 0, stream>>>(x, PK, in_b, P, cnt);

    // 2: main serial chain + fused combine
    k_nade_main<<<NBG * C * HQ, 256, 0, stream>>>(x, PK, P, h_b, Q, cnt, out);
}

// Round 14
// 53.256 us; speedup vs baseline: 4.5005x; 4.5005x over previous
//
#include <hip/hip_runtime.h>
#include <hip/hip_bf16.h>

// Problem constants
#define B 64
#define D 1024
#define H 1024
#define C 32           // chunks along D
#define L (D / C)      // chunk length = 32
#define BG 4           // batch rows per main block
#define NBG (B / BG)   // 16 batch groups
#define HQ 4           // h-quarters
#define HP (H / HQ)    // 256 h per block = 1 h per thread

// DPP quad-perm cross-lane (VALU-speed, no LDS)
__device__ __forceinline__ float dpp_xor1(float v) {
    int i = __builtin_bit_cast(int, v);
    i = __builtin_amdgcn_mov_dpp(i, 0xB1, 0xF, 0xF, true);  // quad_perm [1,0,3,2]
    return __builtin_bit_cast(float, i);
}
__device__ __forceinline__ float dpp_xor2(float v) {
    int i = __builtin_bit_cast(int, v);
    i = __builtin_amdgcn_mov_dpp(i, 0x4E, 0xF, 0xF, true);  // quad_perm [2,3,0,1]
    return __builtin_bit_cast(float, i);
}

// round-to-nearest-even f32 -> bf16 bits (low 16)
__device__ __forceinline__ unsigned bf16r(float f) {
    unsigned u = __builtin_bit_cast(unsigned, f);
    return (u + 0x7FFFu + ((u >> 16) & 1u)) >> 16;
}

// ---------------------------------------------------------------------------
// Kernel 0: pack PK[d][h] = bf16(h_W[d,h])<<16 | bf16(in_W[h,d])
// ---------------------------------------------------------------------------
__global__ void k_pack(const float* __restrict__ in_W,
                       const float* __restrict__ h_W,
                       unsigned* __restrict__ PK) {
    __shared__ float tile[32][33];
    int bx = blockIdx.x * 32;  // d-range
    int by = blockIdx.y * 32;  // h-range
    int tx = threadIdx.x;      // 0..31
    int ty = threadIdx.y;      // 0..7
    #pragma unroll
    for (int r = 0; r < 32; r += 8)
        tile[ty + r][tx] = in_W[(size_t)(by + ty + r) * D + (bx + tx)];
    __syncthreads();
    #pragma unroll
    for (int r = 0; r < 32; r += 8) {
        int d = bx + ty + r;
        int h = by + tx;
        float hw = h_W[(size_t)d * H + h];       // coalesced in tx
        float iw = tile[tx][ty + r];             // in_W[h][d]
        PK[(size_t)d * H + h] = (bf16r(hw) << 16) | bf16r(iw);
    }
}

// ---------------------------------------------------------------------------
// Kernel 1: direct exclusive per-chunk prefix (replaces chunk_sums + scan;
// verified in R13). block = (b, hq): 256 blocks; thread owns one h.
// P[b][c][h] = in_b[h] + sum_{d < c*L} x[b,d] * in_W[h,d]
// ---------------------------------------------------------------------------
__global__ void __launch_bounds__(256)
k_prefix(const float* __restrict__ x,
         const unsigned* __restrict__ PK,
         const float* __restrict__ in_b,
         float* __restrict__ P) {
    int blk = blockIdx.x;
    int b  = blk >> 2;         // 0..63
    int hq = blk & 3;          // 0..3
    int tid = threadIdx.x;
    int h  = hq * HP + tid;

    __shared__ float xs[D];
    {
        const float4* xrow = reinterpret_cast<const float4*>(&x[(size_t)b * D]);
        float4 v = xrow[tid];
        reinterpret_cast<float4*>(xs)[tid] = v;
    }
    __syncthreads();

    float run = in_b[h];
    #pragma unroll 1
    for (int c = 0; c < C; ++c) {
        P[((size_t)b * C + c) * H + h] = run;
        #pragma unroll
        for (int j = 0; j < L; ++j) {
            int d = c * L + j;
            unsigned pk = PK[(size_t)d * H + h];
            float w = __builtin_bit_cast(float, pk << 16);   // in_W[h,d]
            run = fmaf(xs[d], w, run);
        }
    }
}

// ---------------------------------------------------------------------------
// Kernel 2: main NADE chain (R12's exact verified body — no atomics/fences).
// block = (bg, c, hq); thread owns one h; 4 batch rows per thread; one packed
// weight load per iteration; barrier-free inner loop (quad-DPP reduce +
// keeper-lane stash, predicated FMA recurrence). Writes Q[hq][b][d].
// ---------------------------------------------------------------------------
__global__ void __launch_bounds__(256)
k_nade_main(const float* __restrict__ x,
            const unsigned* __restrict__ PK,
            const float* __restrict__ P,   // prefixes incl. in_b [B,C,H]
            float* __restrict__ Q) {       // [HQ][B][D] partial dots
    int blk = blockIdx.x;
    int bg  = blk >> 7;
    int chq = blk & 127;
    int c   = chq >> 2;
    int hq  = chq & 3;
    int b0  = bg * BG;
    int tid = threadIdx.x;
    int h   = hq * HP + tid;
    int lane = tid & 63;
    int wv = tid >> 6;
    int ph = lane & 3;

    __shared__ float4 xs4[L];
    __shared__ float red[4][BG][L];
    if (tid < L) {
        int i = c * L + tid;
        xs4[tid] = make_float4(x[(size_t)b0 * D + i],
                               x[(size_t)(b0 + 1) * D + i],
                               x[(size_t)(b0 + 2) * D + i],
                               x[(size_t)(b0 + 3) * D + i]);
    }

    float a0 = P[((size_t)b0 * C + c) * H + h];
    float a1 = P[((size_t)(b0 + 1) * C + c) * H + h];
    float a2 = P[((size_t)(b0 + 2) * C + c) * H + h];
    float a3 = P[((size_t)(b0 + 3) * C + c) * H + h];

    __syncthreads();

    bool k0 = (ph == 0), k1 = (ph == 1), k2 = (ph == 2), k3 = (ph == 3);

    float pr0[8], pr1[8], pr2[8], pr3[8];
    #pragma unroll
    for (int s = 0; s < 8; ++s) { pr0[s] = 0.f; pr1[s] = 0.f; pr2[s] = 0.f; pr3[s] = 0.f; }

    #pragma unroll
    for (int il = 0; il < L; ++il) {
        int i = c * L + il;
        unsigned pk = PK[(size_t)i * H + h];
        float w  = __builtin_bit_cast(float, pk & 0xFFFF0000u);  // h_W[i,h]
        float wt = __builtin_bit_cast(float, pk << 16);          // in_W[h,i]
        float4 xf = xs4[il];
        int s = il >> 2;
        bool keep = (il & 3) == 0 ? k0 : ((il & 3) == 1 ? k1 : ((il & 3) == 2 ? k2 : k3));

        float p0 = fmaxf(a0, 0.f) * w;
        float t0 = p0 + dpp_xor1(p0); t0 = t0 + dpp_xor2(t0);
        pr0[s] = keep ? t0 : pr0[s];
        a0 = fmaf(xf.x, wt, a0);

        float p1 = fmaxf(a1, 0.f) * w;
        float t1 = p1 + dpp_xor1(p1); t1 = t1 + dpp_xor2(t1);
        pr1[s] = keep ? t1 : pr1[s];
        a1 = fmaf(xf.y, wt, a1);

        float p2 = fmaxf(a2, 0.f) * w;
        float t2 = p2 + dpp_xor1(p2); t2 = t2 + dpp_xor2(t2);
        pr2[s] = keep ? t2 : pr2[s];
        a2 = fmaf(xf.z, wt, a2);

        float p3 = fmaxf(a3, 0.f) * w;
        float t3 = p3 + dpp_xor1(p3); t3 = t3 + dpp_xor2(t3);
        pr3[s] = keep ? t3 : pr3[s];
        a3 = fmaf(xf.w, wt, a3);
    }

    // cross-quad reduce within the wave (sum over 16 quads = 64 h)
    #pragma unroll
    for (int s = 0; s < 8; ++s) {
        float v;
        v = pr0[s];
        v += __shfl_xor(v, 4, 64); v += __shfl_xor(v, 8, 64);
        v += __shfl_xor(v, 16, 64); v += __shfl_xor(v, 32, 64);
        pr0[s] = v;
        v = pr1[s];
        v += __shfl_xor(v, 4, 64); v += __shfl_xor(v, 8, 64);
        v += __shfl_xor(v, 16, 64); v += __shfl_xor(v, 32, 64);
        pr1[s] = v;
        v = pr2[s];
        v += __shfl_xor(v, 4, 64); v += __shfl_xor(v, 8, 64);
        v += __shfl_xor(v, 16, 64); v += __shfl_xor(v, 32, 64);
        pr2[s] = v;
        v = pr3[s];
        v += __shfl_xor(v, 4, 64); v += __shfl_xor(v, 8, 64);
        v += __shfl_xor(v, 16, 64); v += __shfl_xor(v, 32, 64);
        pr3[s] = v;
    }

    if (lane < 4) {
        #pragma unroll
        for (int s = 0; s < 8; ++s) {
            red[wv][0][s * 4 + lane] = pr0[s];
            red[wv][1][s * 4 + lane] = pr1[s];
            red[wv][2][s * 4 + lane] = pr2[s];
            red[wv][3][s * 4 + lane] = pr3[s];
        }
    }
    __syncthreads();

    if (tid < BG * L) {
        int b = tid >> 5;
        int il = tid & 31;
        float t = red[0][b][il] + red[1][b][il] + red[2][b][il] + red[3][b][il];
        Q[((size_t)hq * B + (b0 + b)) * D + c * L + il] = t;
    }
}

// ---------------------------------------------------------------------------
// Kernel 3: combine h-quarter partials + bias + sigmoid
// ---------------------------------------------------------------------------
__global__ void __launch_bounds__(256)
k_combine(const float* __restrict__ Q,
          const float* __restrict__ h_b,
          float* __restrict__ out) {
    int idx = blockIdx.x * blockDim.x + threadIdx.x;  // 0 .. B*D-1
    if (idx >= B * D) return;
    int d = idx & (D - 1);
    float t = Q[idx] + Q[(size_t)B * D + idx] + Q[2 * (size_t)B * D + idx]
            + Q[3 * (size_t)B * D + idx] + h_b[d];
    out[idx] = 1.0f / (1.0f + expf(-t));
}

// ---------------------------------------------------------------------------
extern "C" void kernel_launch(void* const* d_in, const int* in_sizes, int n_in,
                              void* d_out, int out_size, void* d_ws, size_t ws_size,
                              hipStream_t stream) {
    const float* x    = (const float*)d_in[0];  // [B, D]
    const float* in_W = (const float*)d_in[1];  // [H, D]
    const float* in_b = (const float*)d_in[2];  // [H]
    const float* h_W  = (const float*)d_in[3];  // [D, H]
    const float* h_b  = (const float*)d_in[4];  // [D]
    float* out = (float*)d_out;                 // [B, D]

    unsigned* PK = (unsigned*)d_ws;             // [D, H] packed   4 MB
    float* P  = (float*)(PK + (size_t)D * H);   // [B, C, H]       8 MB
    float* Q  = P + (size_t)B * C * H;          // [HQ, B, D]      1 MB

    // 0: pack weights (bf16 pair per dword; includes in_W transpose)
    dim3 tb(32, 8);
    dim3 tg(D / 32, H / 32);
    k_pack<<<tg, tb, 0, stream>>>(in_W, h_W, PK);

    // 1: direct exclusive prefix (replaces chunk_sums + scan)
    k_prefix<<<B * HQ, 256, 0, stream>>>(x, PK, in_b, P);

    // 2: main serial chain (R12 verified body)
    k_nade_main<<<NBG * C * HQ, 256, 0, stream>>>(x, PK, P, Q);

    // 3: combine quarters + sigmoid
    k_combine<<<(B * D + 255) / 256, 256, 0, stream>>>(Q, h_b, out);
}

// Round 16
// 39.895 us; speedup vs baseline: 6.0077x; 1.3349x over previous
//
#include <hip/hip_runtime.h>
#include <hip/hip_bf16.h>

// Problem constants
#define B 64
#define D 1024
#define H 1024
#define C 32           // chunks along D
#define L (D / C)      // chunk length = 32
#define BG 4           // batch rows per block (register-shared weight loads)
#define NBG (B / BG)   // 16 batch groups
#define HQ 4           // h-quarters
#define HP (H / HQ)    // 256 h per block = 1 h per thread

// DPP quad-perm cross-lane (VALU-speed, no LDS). NOTE: keep the builtin form —
// LLVM's GCNDPPCombine folds mov_dpp+add into v_add_f32_dpp with correct
// hazard handling; hand-written asm for the fused op races (R15 lesson).
__device__ __forceinline__ float dpp_xor1(float v) {
    int i = __builtin_bit_cast(int, v);
    i = __builtin_amdgcn_mov_dpp(i, 0xB1, 0xF, 0xF, true);  // quad_perm [1,0,3,2]
    return __builtin_bit_cast(float, i);
}
__device__ __forceinline__ float dpp_xor2(float v) {
    int i = __builtin_bit_cast(int, v);
    i = __builtin_amdgcn_mov_dpp(i, 0x4E, 0xF, 0xF, true);  // quad_perm [2,3,0,1]
    return __builtin_bit_cast(float, i);
}

// round-to-nearest-even f32 -> bf16 bits (low 16)
__device__ __forceinline__ unsigned bf16r(float f) {
    unsigned u = __builtin_bit_cast(unsigned, f);
    return (u + 0x7FFFu + ((u >> 16) & 1u)) >> 16;
}

// ---------------------------------------------------------------------------
// Kernel 0: pack PK[d][h] = bf16(h_W[d,h])<<16 | bf16(in_W[h,d])
// ---------------------------------------------------------------------------
__global__ void k_pack(const float* __restrict__ in_W,
                       const float* __restrict__ h_W,
                       unsigned* __restrict__ PK) {
    __shared__ float tile[32][33];
    int bx = blockIdx.x * 32;  // d-range
    int by = blockIdx.y * 32;  // h-range
    int tx = threadIdx.x;      // 0..31
    int ty = threadIdx.y;      // 0..7
    #pragma unroll
    for (int r = 0; r < 32; r += 8)
        tile[ty + r][tx] = in_W[(size_t)(by + ty + r) * D + (bx + tx)];
    __syncthreads();
    #pragma unroll
    for (int r = 0; r < 32; r += 8) {
        int d = bx + ty + r;
        int h = by + tx;
        float hw = h_W[(size_t)d * H + h];       // coalesced in tx
        float iw = tile[tx][ty + r];             // in_W[h][d]
        PK[(size_t)d * H + h] = (bf16r(hw) << 16) | bf16r(iw);
    }
}

// ---------------------------------------------------------------------------
// Kernel 1: per-chunk rank-1 sums. block = (bg, c, hq); thread owns one h;
// 4 batch rows share each packed weight dword in registers.
// S[b,c,h] = sum_{j in chunk c} x[b,j]*in_W[h,j]   (x exactly {0,1})
// ---------------------------------------------------------------------------
__global__ void __launch_bounds__(256)
k_chunk_sums(const float* __restrict__ x,
             const unsigned* __restrict__ PK,
             float* __restrict__ S) {
    int blk = blockIdx.x;
    int bg  = blk >> 7;          // /128
    int chq = blk & 127;
    int c   = chq >> 2;
    int hq  = chq & 3;
    int b0  = bg * BG;
    int tid = threadIdx.x;
    int h   = hq * HP + tid;

    __shared__ float4 xs4[L];
    if (tid < L) {
        int i = c * L + tid;
        xs4[tid] = make_float4(x[(size_t)b0 * D + i],
                               x[(size_t)(b0 + 1) * D + i],
                               x[(size_t)(b0 + 2) * D + i],
                               x[(size_t)(b0 + 3) * D + i]);
    }
    __syncthreads();

    float acc0 = 0.f, acc1 = 0.f, acc2 = 0.f, acc3 = 0.f;
    #pragma unroll
    for (int j = 0; j < L; ++j) {
        unsigned pk = PK[(size_t)(c * L + j) * H + h];
        float w = __builtin_bit_cast(float, pk << 16);   // in_W[h, cL+j]
        float4 xf = xs4[j];
        acc0 = fmaf(xf.x, w, acc0);
        acc1 = fmaf(xf.y, w, acc1);
        acc2 = fmaf(xf.z, w, acc2);
        acc3 = fmaf(xf.w, w, acc3);
    }
    S[((size_t)b0 * C + c) * H + h]       = acc0;
    S[((size_t)(b0 + 1) * C + c) * H + h] = acc1;
    S[((size_t)(b0 + 2) * C + c) * H + h] = acc2;
    S[((size_t)(b0 + 3) * C + c) * H + h] = acc3;
}

// ---------------------------------------------------------------------------
// Kernel 2: in-place exclusive scan over chunks
// ---------------------------------------------------------------------------
__global__ void k_scan(float* __restrict__ S) {
    int tid = blockIdx.x * blockDim.x + threadIdx.x;  // 0 .. B*H-1
    if (tid >= B * H) return;
    int b = tid / H;
    int h = tid % H;
    float run = 0.f;
    #pragma unroll
    for (int c = 0; c < C; ++c) {
        int idx = (b * C + c) * H + h;
        float v = S[idx];
        S[idx] = run;
        run += v;
    }
}

// ---------------------------------------------------------------------------
// Kernel 3: main NADE chain. block = (bg, c, hq); thread owns one h;
// 4 batch rows per thread. ONE packed weight load per iteration:
// w = pk & 0xFFFF0000 (h_W), wt = pk << 16 (in_W). Barrier-free inner loop,
// quad-DPP reduce + keeper-lane stash, predicated FMA recurrence.
// Writes per-quarter partial dots Q[hq][b][d].
// ---------------------------------------------------------------------------
__global__ void __launch_bounds__(256)
k_nade_main(const float* __restrict__ x,
            const unsigned* __restrict__ PK,
            const float* __restrict__ in_b,
            const float* __restrict__ P,   // exclusive chunk prefixes [B,C,H]
            float* __restrict__ Q) {       // [HQ][B][D] partial dots
    int blk = blockIdx.x;
    int bg  = blk >> 7;
    int chq = blk & 127;
    int c   = chq >> 2;
    int hq  = chq & 3;
    int b0  = bg * BG;
    int tid = threadIdx.x;
    int h   = hq * HP + tid;
    int lane = tid & 63;
    int wv = tid >> 6;
    int ph = lane & 3;

    __shared__ float4 xs4[L];
    __shared__ float red[4][BG][L];
    if (tid < L) {
        int i = c * L + tid;
        xs4[tid] = make_float4(x[(size_t)b0 * D + i],
                               x[(size_t)(b0 + 1) * D + i],
                               x[(size_t)(b0 + 2) * D + i],
                               x[(size_t)(b0 + 3) * D + i]);
    }

    float ib = in_b[h];
    float a0 = P[((size_t)b0 * C + c) * H + h] + ib;
    float a1 = P[((size_t)(b0 + 1) * C + c) * H + h] + ib;
    float a2 = P[((size_t)(b0 + 2) * C + c) * H + h] + ib;
    float a3 = P[((size_t)(b0 + 3) * C + c) * H + h] + ib;

    __syncthreads();

    bool k0 = (ph == 0), k1 = (ph == 1), k2 = (ph == 2), k3 = (ph == 3);

    float pr0[8], pr1[8], pr2[8], pr3[8];
    #pragma unroll
    for (int s = 0; s < 8; ++s) { pr0[s] = 0.f; pr1[s] = 0.f; pr2[s] = 0.f; pr3[s] = 0.f; }

    #pragma unroll
    for (int il = 0; il < L; ++il) {
        int i = c * L + il;
        unsigned pk = PK[(size_t)i * H + h];
        float w  = __builtin_bit_cast(float, pk & 0xFFFF0000u);  // h_W[i,h]
        float wt = __builtin_bit_cast(float, pk << 16);          // in_W[h,i]
        float4 xf = xs4[il];
        int s = il >> 2;
        bool keep = (il & 3) == 0 ? k0 : ((il & 3) == 1 ? k1 : ((il & 3) == 2 ? k2 : k3));

        float p0 = fmaxf(a0, 0.f) * w;
        float t0 = p0 + dpp_xor1(p0); t0 = t0 + dpp_xor2(t0);
        pr0[s] = keep ? t0 : pr0[s];
        a0 = fmaf(xf.x, wt, a0);

        float p1 = fmaxf(a1, 0.f) * w;
        float t1 = p1 + dpp_xor1(p1); t1 = t1 + dpp_xor2(t1);
        pr1[s] = keep ? t1 : pr1[s];
        a1 = fmaf(xf.y, wt, a1);

        float p2 = fmaxf(a2, 0.f) * w;
        float t2 = p2 + dpp_xor1(p2); t2 = t2 + dpp_xor2(t2);
        pr2[s] = keep ? t2 : pr2[s];
        a2 = fmaf(xf.z, wt, a2);

        float p3 = fmaxf(a3, 0.f) * w;
        float t3 = p3 + dpp_xor1(p3); t3 = t3 + dpp_xor2(t3);
        pr3[s] = keep ? t3 : pr3[s];
        a3 = fmaf(xf.w, wt, a3);
    }

    // cross-quad reduce within the wave (sum over 16 quads = 64 h)
    #pragma unroll
    for (int s = 0; s < 8; ++s) {
        float v;
        v = pr0[s];
        v += __shfl_xor(v, 4, 64); v += __shfl_xor(v, 8, 64);
        v += __shfl_xor(v, 16, 64); v += __shfl_xor(v, 32, 64);
        pr0[s] = v;
        v = pr1[s];
        v += __shfl_xor(v, 4, 64); v += __shfl_xor(v, 8, 64);
        v += __shfl_xor(v, 16, 64); v += __shfl_xor(v, 32, 64);
        pr1[s] = v;
        v = pr2[s];
        v += __shfl_xor(v, 4, 64); v += __shfl_xor(v, 8, 64);
        v += __shfl_xor(v, 16, 64); v += __shfl_xor(v, 32, 64);
        pr2[s] = v;
        v = pr3[s];
        v += __shfl_xor(v, 4, 64); v += __shfl_xor(v, 8, 64);
        v += __shfl_xor(v, 16, 64); v += __shfl_xor(v, 32, 64);
        pr3[s] = v;
    }

    if (lane < 4) {
        #pragma unroll
        for (int s = 0; s < 8; ++s) {
            red[wv][0][s * 4 + lane] = pr0[s];
            red[wv][1][s * 4 + lane] = pr1[s];
            red[wv][2][s * 4 + lane] = pr2[s];
            red[wv][3][s * 4 + lane] = pr3[s];
        }
    }
    __syncthreads();

    if (tid < BG * L) {
        int b = tid >> 5;
        int il = tid & 31;
        float t = red[0][b][il] + red[1][b][il] + red[2][b][il] + red[3][b][il];
        Q[((size_t)hq * B + (b0 + b)) * D + c * L + il] = t;
    }
}

// ---------------------------------------------------------------------------
// Kernel 4: combine h-quarter partials + bias + sigmoid
// ---------------------------------------------------------------------------
__global__ void __launch_bounds__(256)
k_combine(const float* __restrict__ Q,
          const float* __restrict__ h_b,
          float* __restrict__ out) {
    int idx = blockIdx.x * blockDim.x + threadIdx.x;  // 0 .. B*D-1
    if (idx >= B * D) return;
    int d = idx & (D - 1);
    float t = Q[idx] + Q[(size_t)B * D + idx] + Q[2 * (size_t)B * D + idx]
            + Q[3 * (size_t)B * D + idx] + h_b[d];
    out[idx] = 1.0f / (1.0f + expf(-t));
}

// ---------------------------------------------------------------------------
extern "C" void kernel_launch(void* const* d_in, const int* in_sizes, int n_in,
                              void* d_out, int out_size, void* d_ws, size_t ws_size,
                              hipStream_t stream) {
    const float* x    = (const float*)d_in[0];  // [B, D]
    const float* in_W = (const float*)d_in[1];  // [H, D]
    const float* in_b = (const float*)d_in[2];  // [H]
    const float* h_W  = (const float*)d_in[3];  // [D, H]
    const float* h_b  = (const float*)d_in[4];  // [D]
    float* out = (float*)d_out;                 // [B, D]

    unsigned* PK = (unsigned*)d_ws;             // [D, H] packed   4 MB
    float* S  = (float*)(PK + (size_t)D * H);   // [B, C, H]       8 MB
    float* Q  = S + (size_t)B * C * H;          // [HQ, B, D]      1 MB

    // 0: pack weights (bf16 pair per dword; includes in_W transpose)
    dim3 tb(32, 8);
    dim3 tg(D / 32, H / 32);
    k_pack<<<tg, tb, 0, stream>>>(in_W, h_W, PK);

    // 1: chunk sums (packed weights, BG=4 register reuse)
    k_chunk_sums<<<NBG * C * HQ, 256, 0, stream>>>(x, PK, S);

    // 2: exclusive scan over chunks (in place)
    k_scan<<<(B * H + 255) / 256, 256, 0, stream>>>(S);

    // 3: main serial chain (single packed weight load per iteration)
    k_nade_main<<<NBG * C * HQ, 256, 0, stream>>>(x, PK, in_b, S, Q);

    // 4: combine quarters + sigmoid
    k_combine<<<(B * D + 255) / 256, 256, 0, stream>>>(Q, h_b, out);
}